// Round 2
// baseline (2715.642 us; speedup 1.0000x reference)
//
#include <hip/hip_runtime.h>
#include <hip/hip_fp16.h>

// GRU_23613730193671 on MI355X (gfx950) — round 2: fused 2-layer persistent scan
// B=256 T=256 D=128 H=512; out = fc2(relu(fc1(relu(hT_layer1))))
//
// Key changes vs round 1 (which was fully decorrelated = structural bug):
//  - ws use cut 73 MB -> ~6.7 MB (y0 materialization removed; 2-step rings).
//    Round-1's y0 buffer may have exceeded ws_size -> garbage.
//  - Both layers fused in ONE kernel, pipelined: step u does L0(t=u) and
//    L1(t=u-1). 257 group barriers total instead of 512.
//  - Group barrier uses system-scope acq-rel atomics (strongest coherence).
//  - LDS: merged A-panel As[16][1152] = [x(128) | h0(512) | h1(512)] fp16
//    (36864B) + reused partials ghp[4][16][100] (25600B) + anx[16][32]
//    (2048B) = 64512B <= 64KB workgroup limit.
//  - 256 blocks = 16 batch-groups x 16 col-groups; block = 16 rows x 32 cols;
//    W fragments in registers (~312 VGPR), fp16 MFMA 16x16x32, fp32 gates.

#define B_  256
#define T_  256
#define D_  128
#define H_  512
#define G3  1536

typedef _Float16 h8  __attribute__((ext_vector_type(8)));
typedef _Float16 h2v __attribute__((ext_vector_type(2)));
typedef float    f4  __attribute__((ext_vector_type(4)));

#define MFMA16(a, b, c) __builtin_amdgcn_mfma_f32_16x16x32_f16((a), (b), (c), 0, 0, 0)

// rotate 16B chunks within aligned groups of 8 by row index -> breaks the
// power-of-2 row stride; 2 lanes/bank aliasing is free (m136).
__device__ __forceinline__ int swz(int c, int r) { return (c & ~7) | ((c + r) & 7); }

__device__ __forceinline__ float sigmoid_f(float v) { return 1.f / (1.f + __expf(-v)); }
__device__ __forceinline__ float tanh_f(float v) {
    float ex = __expf(2.f * v);
    return 1.f - 2.f / (ex + 1.f);
}

// ---------------------------------------------------------------------------
__global__ void convert_weights(const float* __restrict__ Wih0,
                                const float* __restrict__ Whh0,
                                const float* __restrict__ Wih1,
                                const float* __restrict__ Whh1,
                                _Float16* __restrict__ Wcat0,
                                _Float16* __restrict__ Wcat1) {
    int g = blockIdx.x;  // 0..1535 (gate-row)
    for (int k = threadIdx.x; k < D_; k += blockDim.x)
        Wcat0[(size_t)g * 640 + k] = (_Float16)Wih0[(size_t)g * D_ + k];
    for (int k = threadIdx.x; k < H_; k += blockDim.x) {
        Wcat0[(size_t)g * 640 + 128 + k]  = (_Float16)Whh0[(size_t)g * H_ + k];
        Wcat1[(size_t)g * 1024 + k]       = (_Float16)Wih1[(size_t)g * H_ + k];
        Wcat1[(size_t)g * 1024 + 512 + k] = (_Float16)Whh1[(size_t)g * H_ + k];
    }
}

// ---------------------------------------------------------------------------
// 16-block (one batch-group) barrier. Monotone counter, never reset.
// System-scope acq-rel: release flushes this XCD's dirty lines past L2;
// acquire invalidates stale L1/L2 lines before the post-barrier reads.
__device__ __forceinline__ void group_barrier(int* c, int target) {
    __syncthreads();   // all waves' global stores drained (vmcnt0 before barrier)
    if (threadIdx.x == 0) {
        __hip_atomic_fetch_add(c, 1, __ATOMIC_RELEASE, __HIP_MEMORY_SCOPE_SYSTEM);
        int v;
        do {
            __builtin_amdgcn_s_sleep(2);
            v = __hip_atomic_load(c, __ATOMIC_ACQUIRE, __HIP_MEMORY_SCOPE_SYSTEM);
        } while (v < target);
    }
    __syncthreads();
}

// ---------------------------------------------------------------------------
// Fused scan. Step u: L0 computes h0(u) (u<256), L1 computes h1(u-1) (u>=1).
// A-panel columns: [ x_u (128) | h0(u-1) (512) | h1(u-2) (512) ] -> chunks
// (8 halfs each): x 0..15, h0 16..79, h1 80..143.
// L0 K-window: chunks 0..79 (K=640, 20 ksteps, 5/wave; ksteps 0..3 = x part).
// L1 K-window: chunks 16..143 (K=1024, 32 ksteps, 8/wave; waves 0,1 = y0 part).
__global__ __launch_bounds__(256, 1) void gru_fused(
    const float* __restrict__ x,
    const _Float16* __restrict__ Wcat0, const _Float16* __restrict__ Wcat1,
    const float* __restrict__ bih0, const float* __restrict__ bhh0,
    const float* __restrict__ bih1, const float* __restrict__ bhh1,
    _Float16* __restrict__ h0ring,   // [2][B][H]
    _Float16* __restrict__ h1ring,   // [2][B][H]
    float* __restrict__ hT,          // [B][H] final layer-1 hidden (fp32)
    int* __restrict__ ctrbase) {
    __shared__ __attribute__((aligned(16))) _Float16 As[16 * 1152];
    __shared__ float ghp[4][16][100];
    __shared__ float anx[16][32];

    const int tid  = threadIdx.x;
    const int bg   = blockIdx.x & 15;
    const int cg   = blockIdx.x >> 4;
    const int wave = tid >> 6;
    const int lane = tid & 63;
    const int l15  = lane & 15;
    const int q    = lane >> 4;
    const int b0   = bg * 16;
    const int hc0  = cg * 32;
    int* myctr = (int*)((char*)ctrbase + bg * 64);

    // ---- W fragments in registers (B-operand: col n = l15, k = q*8+j) ----
    h8 wf0[5][6];
#pragma unroll
    for (int s = 0; s < 5; ++s) {
        const int kh = (wave * 5 + s) * 32 + q * 8;
#pragma unroll
        for (int nt = 0; nt < 6; ++nt) {
            const int grow = (nt >> 1) * H_ + hc0 + (nt & 1) * 16 + l15;
            wf0[s][nt] = *(const h8*)(Wcat0 + (size_t)grow * 640 + kh);
        }
    }
    h8 wf1[8][6];
#pragma unroll
    for (int s = 0; s < 8; ++s) {
        const int kh = (wave * 8 + s) * 32 + q * 8;
#pragma unroll
        for (int nt = 0; nt < 6; ++nt) {
            const int grow = (nt >> 1) * H_ + hc0 + (nt & 1) * 16 + l15;
            wf1[s][nt] = *(const h8*)(Wcat1 + (size_t)grow * 1024 + kh);
        }
    }
    // ---- per-thread epilogue biases (thread -> (row er, cols jj..jj+1)) ----
    float br0[2], bz0[2], bi0[2], bh0[2], br1[2], bz1[2], bi1[2], bh1[2];
    {
        const int jj = (tid & 15) * 2;
#pragma unroll
        for (int e = 0; e < 2; ++e) {
            const int col = hc0 + jj + e;
            br0[e] = bih0[col] + bhh0[col];
            bz0[e] = bih0[H_ + col] + bhh0[H_ + col];
            bi0[e] = bih0[2 * H_ + col];
            bh0[e] = bhh0[2 * H_ + col];
            br1[e] = bih1[col] + bhh1[col];
            bz1[e] = bih1[H_ + col] + bhh1[H_ + col];
            bi1[e] = bih1[2 * H_ + col];
            bh1[e] = bhh1[2 * H_ + col];
        }
    }

#pragma unroll 1
    for (int u = 0; u <= T_; ++u) {
        // ================= stage A-panel =================
        {
            const int r = tid >> 4, c16 = tid & 15;
            if (u < T_) {  // x_u -> chunks 0..15
                const float* xp = x + ((size_t)(b0 + r) * T_ + u) * D_ + c16 * 8;
                float4 v0 = *(const float4*)(xp);
                float4 v1 = *(const float4*)(xp + 4);
                h8 hx;
                hx[0] = (_Float16)v0.x; hx[1] = (_Float16)v0.y;
                hx[2] = (_Float16)v0.z; hx[3] = (_Float16)v0.w;
                hx[4] = (_Float16)v1.x; hx[5] = (_Float16)v1.y;
                hx[6] = (_Float16)v1.z; hx[7] = (_Float16)v1.w;
                *(h8*)&As[r * 1152 + swz(c16, r) * 8] = hx;
            }
            // h0(u-1) -> chunks 16..79   (parity (u-1)&1 == (u+1)&1)
            const _Float16* h0p = h0ring + (size_t)((u + 1) & 1) * (B_ * H_) + (size_t)(b0 + r) * H_;
#pragma unroll
            for (int i = 0; i < 4; ++i) {
                const int lc = c16 + i * 16;
                h8 hv = {};
                if (u > 0) hv = *(const h8*)(h0p + lc * 8);
                *(h8*)&As[r * 1152 + swz(16 + lc, r) * 8] = hv;
            }
            // h1(u-2) -> chunks 80..143  (parity (u-2)&1 == u&1)
            const _Float16* h1p = h1ring + (size_t)(u & 1) * (B_ * H_) + (size_t)(b0 + r) * H_;
#pragma unroll
            for (int i = 0; i < 4; ++i) {
                const int lc = c16 + i * 16;
                h8 hv = {};
                if (u > 1) hv = *(const h8*)(h1p + lc * 8);
                *(h8*)&As[r * 1152 + swz(80 + lc, r) * 8] = hv;
            }
        }
        __syncthreads();
        // ================= L0 MFMA =================
        if (u < T_) {
            f4 arz0 = {0,0,0,0}, arz1 = {0,0,0,0}, arz2 = {0,0,0,0}, arz3 = {0,0,0,0};
            f4 anx0 = {0,0,0,0}, anx1 = {0,0,0,0}, anh0 = {0,0,0,0}, anh1 = {0,0,0,0};
#pragma unroll
            for (int s = 0; s < 5; ++s) {
                const int kstep = wave * 5 + s;
                const int c = kstep * 4 + q;           // chunk 0..79
                h8 a = *(const h8*)&As[l15 * 1152 + swz(c, l15) * 8];
                arz0 = MFMA16(a, wf0[s][0], arz0);
                arz1 = MFMA16(a, wf0[s][1], arz1);
                arz2 = MFMA16(a, wf0[s][2], arz2);
                arz3 = MFMA16(a, wf0[s][3], arz3);
                if (kstep < 4) {                       // x part (wave 0 only)
                    anx0 = MFMA16(a, wf0[s][4], anx0);
                    anx1 = MFMA16(a, wf0[s][5], anx1);
                } else {                               // h part
                    anh0 = MFMA16(a, wf0[s][4], anh0);
                    anh1 = MFMA16(a, wf0[s][5], anh1);
                }
            }
#pragma unroll
            for (int i = 0; i < 4; ++i) {              // C/D: row=q*4+i, col=l15
                float* row = &ghp[wave][q * 4 + i][0];
                row[ 0 + l15] = arz0[i];
                row[16 + l15] = arz1[i];
                row[32 + l15] = arz2[i];
                row[48 + l15] = arz3[i];
                row[64 + l15] = anh0[i];
                row[80 + l15] = anh1[i];
            }
            if (wave == 0) {
#pragma unroll
                for (int i = 0; i < 4; ++i) {
                    anx[q * 4 + i][l15]      = anx0[i];
                    anx[q * 4 + i][16 + l15] = anx1[i];
                }
            }
        }
        __syncthreads();
        // ================= L0 epilogue: h0(u) =================
        if (u < T_) {
            const int er = tid >> 4;
            const int jj = (tid & 15) * 2;
            h2v out2;
#pragma unroll
            for (int e = 0; e < 2; ++e) {
                const int j = jj + e;
                float gr = 0.f, gz = 0.f, ghn = 0.f;
#pragma unroll
                for (int w = 0; w < 4; ++w) {
                    gr  += ghp[w][er][j];
                    gz  += ghp[w][er][32 + j];
                    ghn += ghp[w][er][64 + j];
                }
                const float gxn = anx[er][j];
                const float rr = sigmoid_f(gr + br0[e]);
                const float zz = sigmoid_f(gz + bz0[e]);
                const float nn = tanh_f(gxn + bi0[e] + rr * (ghn + bh0[e]));
                const int hcol = hc0 + j;
                const float hp = (float)As[er * 1152 + swz(16 + (hcol >> 3), er) * 8 + (hcol & 7)];
                out2[e] = (_Float16)((1.f - zz) * nn + zz * hp);
            }
            *(h2v*)(h0ring + (size_t)(u & 1) * (B_ * H_) + (size_t)(b0 + er) * H_ + hc0 + jj) = out2;
        }
        __syncthreads();   // ghp reuse guard
        // ================= L1 MFMA =================
        if (u > 0) {
            f4 arz0 = {0,0,0,0}, arz1 = {0,0,0,0}, arz2 = {0,0,0,0}, arz3 = {0,0,0,0};
            f4 an0 = {0,0,0,0}, an1 = {0,0,0,0};   // nx for waves 0,1; nh for 2,3
#pragma unroll
            for (int s = 0; s < 8; ++s) {
                const int c = 16 + (wave * 8 + s) * 4 + q;   // chunk 16..143
                h8 a = *(const h8*)&As[l15 * 1152 + swz(c, l15) * 8];
                arz0 = MFMA16(a, wf1[s][0], arz0);
                arz1 = MFMA16(a, wf1[s][1], arz1);
                arz2 = MFMA16(a, wf1[s][2], arz2);
                arz3 = MFMA16(a, wf1[s][3], arz3);
                an0  = MFMA16(a, wf1[s][4], an0);
                an1  = MFMA16(a, wf1[s][5], an1);
            }
#pragma unroll
            for (int i = 0; i < 4; ++i) {
                float* row = &ghp[wave][q * 4 + i][0];
                row[ 0 + l15] = arz0[i];
                row[16 + l15] = arz1[i];
                row[32 + l15] = arz2[i];
                row[48 + l15] = arz3[i];
                row[64 + l15] = an0[i];
                row[80 + l15] = an1[i];
            }
        }
        __syncthreads();
        // ================= L1 epilogue: h1(u-1) =================
        if (u > 0) {
            const int er = tid >> 4;
            const int jj = (tid & 15) * 2;
            h2v out2;
            float hvf[2];
#pragma unroll
            for (int e = 0; e < 2; ++e) {
                const int j = jj + e;
                float gr = 0.f, gz = 0.f;
#pragma unroll
                for (int w = 0; w < 4; ++w) {
                    gr += ghp[w][er][j];
                    gz += ghp[w][er][32 + j];
                }
                const float gxn = ghp[0][er][64 + j] + ghp[1][er][64 + j];
                const float ghn = ghp[2][er][64 + j] + ghp[3][er][64 + j];
                const float rr = sigmoid_f(gr + br1[e]);
                const float zz = sigmoid_f(gz + bz1[e]);
                const float nn = tanh_f(gxn + bi1[e] + rr * (ghn + bh1[e]));
                const int hcol = hc0 + j;
                const float hp = (float)As[er * 1152 + swz(80 + (hcol >> 3), er) * 8 + (hcol & 7)];
                hvf[e] = (1.f - zz) * nn + zz * hp;
                out2[e] = (_Float16)hvf[e];
            }
            *(h2v*)(h1ring + (size_t)((u + 1) & 1) * (B_ * H_) + (size_t)(b0 + er) * H_ + hc0 + jj) = out2;
            if (u == T_) {
                hT[(size_t)(b0 + er) * H_ + hc0 + jj]     = hvf[0];
                hT[(size_t)(b0 + er) * H_ + hc0 + jj + 1] = hvf[1];
            }
        }
        if (u < T_) group_barrier(myctr, 16 * (u + 1));
    }
}

// ---------------------------------------------------------------------------
__global__ __launch_bounds__(128) void head_kernel(
    const float* __restrict__ hT, const float* __restrict__ fc1_w,
    const float* __restrict__ fc1_b, const float* __restrict__ fc2_w,
    const float* __restrict__ fc2_b, float* __restrict__ out) {
    __shared__ float hs[512];
    __shared__ float a1[128];
    const int b = blockIdx.x, tid = threadIdx.x;
    for (int k = tid; k < H_; k += 128) {
        float v = hT[(size_t)b * H_ + k];
        hs[k] = v > 0.f ? v : 0.f;
    }
    __syncthreads();
    float acc = fc1_b[tid];
    const float* wr = fc1_w + (size_t)tid * H_;
    for (int k = 0; k < H_; k += 4) {
        float4 w = *(const float4*)(wr + k);
        acc += w.x * hs[k] + w.y * hs[k + 1] + w.z * hs[k + 2] + w.w * hs[k + 3];
    }
    a1[tid] = acc > 0.f ? acc : 0.f;
    __syncthreads();
    if (tid < 10) {
        float o = fc2_b[tid];
        const float* w2 = fc2_w + (size_t)tid * 128;
        for (int k = 0; k < 128; ++k) o += w2[k] * a1[k];
        out[(size_t)b * 10 + tid] = o;
    }
}

// ---------------------------------------------------------------------------
extern "C" void kernel_launch(void* const* d_in, const int* in_sizes, int n_in,
                              void* d_out, int out_size, void* d_ws, size_t ws_size,
                              hipStream_t stream) {
    const float* x    = (const float*)d_in[0];
    const float* Wih0 = (const float*)d_in[1];
    const float* Whh0 = (const float*)d_in[2];
    const float* bih0 = (const float*)d_in[3];
    const float* bhh0 = (const float*)d_in[4];
    const float* Wih1 = (const float*)d_in[5];
    const float* Whh1 = (const float*)d_in[6];
    const float* bih1 = (const float*)d_in[7];
    const float* bhh1 = (const float*)d_in[8];
    const float* fc1w = (const float*)d_in[9];
    const float* fc1b = (const float*)d_in[10];
    const float* fc2w = (const float*)d_in[11];
    const float* fc2b = (const float*)d_in[12];

    char* ws = (char*)d_ws;
    size_t off = 0;
    int* ctr = (int*)(ws + off); off += 16 * 64;               // 1 KB
    off = (off + 255) & ~(size_t)255;
    _Float16* Wcat0 = (_Float16*)(ws + off); off += (size_t)G3 * 640 * 2;   // 1.97 MB
    off = (off + 255) & ~(size_t)255;
    _Float16* Wcat1 = (_Float16*)(ws + off); off += (size_t)G3 * 1024 * 2;  // 3.15 MB
    off = (off + 255) & ~(size_t)255;
    _Float16* h0ring = (_Float16*)(ws + off); off += (size_t)2 * B_ * H_ * 2;  // 0.5 MB
    _Float16* h1ring = (_Float16*)(ws + off); off += (size_t)2 * B_ * H_ * 2;  // 0.5 MB
    float* hT = (float*)(ws + off); off += (size_t)B_ * H_ * 4;                // 0.5 MB
    // total ~6.7 MB

    hipMemsetAsync(ctr, 0, 16 * 64, stream);  // zero barrier counters

    hipLaunchKernelGGL(convert_weights, dim3(G3), dim3(256), 0, stream,
                       Wih0, Whh0, Wih1, Whh1, Wcat0, Wcat1);
    hipLaunchKernelGGL(gru_fused, dim3(256), dim3(256), 0, stream,
                       x, Wcat0, Wcat1, bih0, bhh0, bih1, bhh1,
                       h0ring, h1ring, hT, ctr);
    hipLaunchKernelGGL(head_kernel, dim3(B_), dim3(128), 0, stream,
                       hT, fc1w, fc1b, fc2w, fc2b, (float*)d_out);
}

// Round 3
// 1617.988 us; speedup vs baseline: 1.6784x; 1.6784x over previous
//
#include <hip/hip_runtime.h>
#include <hip/hip_fp16.h>

// GRU_23613730193671 on MI355X (gfx950) — round 3: cheap cross-XCD coherence
// B=256 T=256 D=128 H=512; out = fc2(relu(fc1(relu(hT_layer1))))
//
// Round-2 result: PASS, 2716 us, MfmaUtil 5%, WRITE_SIZE 130MB -> barrier-bound.
// The system-scope acq/rel barrier emitted full-L2 buffer_wbl2/buffer_inv per
// step (acquire per POLL iteration!), forcing all h-ring traffic to HBM.
//
// Round-3 change: NO fences at all. h-ring exchange uses relaxed AGENT-scope
// atomic loads/stores, which compile to per-access sc0/sc1 cache-bypass ops
// (coherent at the MALL, same mechanism that makes device-scope atomicAdd
// work cross-XCD). Barrier = __syncthreads (drains vmcnt; sc-stores acked at
// coherence point) + relaxed fetch_add + relaxed spin. No L2 flush/inv.
//
// Structure unchanged: 256 persistent blocks = 16 batch-groups x 16 col-groups,
// both GRU layers fused & pipelined (step u: L0(u) and L1(u-1)), W fragments
// in registers, fp16 MFMA 16x16x32, fp32 gates. LDS 64512B, 1 block/CU.

#define B_  256
#define T_  256
#define D_  128
#define H_  512
#define G3  1536

typedef _Float16 h8  __attribute__((ext_vector_type(8)));
typedef _Float16 h2v __attribute__((ext_vector_type(2)));
typedef float    f4  __attribute__((ext_vector_type(4)));
typedef unsigned long long u64;

#define MFMA16(a, b, c) __builtin_amdgcn_mfma_f32_16x16x32_f16((a), (b), (c), 0, 0, 0)

// rotate 16B chunks within aligned groups of 8 by row index -> breaks the
// power-of-2 row stride; 2 lanes/bank aliasing is free (m136).
__device__ __forceinline__ int swz(int c, int r) { return (c & ~7) | ((c + r) & 7); }

__device__ __forceinline__ float sigmoid_f(float v) { return 1.f / (1.f + __expf(-v)); }
__device__ __forceinline__ float tanh_f(float v) {
    float ex = __expf(2.f * v);
    return 1.f - 2.f / (ex + 1.f);
}

// coherent (MALL-level) 16B load as two 8B relaxed agent atomics
__device__ __forceinline__ h8 ld_h8_coh(const _Float16* p) {
    union { u64 q[2]; h8 v; } uu;
    const u64* qp = (const u64*)p;
    uu.q[0] = __hip_atomic_load(qp,     __ATOMIC_RELAXED, __HIP_MEMORY_SCOPE_AGENT);
    uu.q[1] = __hip_atomic_load(qp + 1, __ATOMIC_RELAXED, __HIP_MEMORY_SCOPE_AGENT);
    return uu.v;
}
// coherent 4B store (one h2v pair)
__device__ __forceinline__ void st_h2_coh(_Float16* p, h2v v) {
    union { h2v v; unsigned int ui; } su; su.v = v;
    __hip_atomic_store((unsigned int*)p, su.ui, __ATOMIC_RELAXED, __HIP_MEMORY_SCOPE_AGENT);
}

// ---------------------------------------------------------------------------
__global__ void convert_weights(const float* __restrict__ Wih0,
                                const float* __restrict__ Whh0,
                                const float* __restrict__ Wih1,
                                const float* __restrict__ Whh1,
                                _Float16* __restrict__ Wcat0,
                                _Float16* __restrict__ Wcat1) {
    int g = blockIdx.x;  // 0..1535 (gate-row)
    for (int k = threadIdx.x; k < D_; k += blockDim.x)
        Wcat0[(size_t)g * 640 + k] = (_Float16)Wih0[(size_t)g * D_ + k];
    for (int k = threadIdx.x; k < H_; k += blockDim.x) {
        Wcat0[(size_t)g * 640 + 128 + k]  = (_Float16)Whh0[(size_t)g * H_ + k];
        Wcat1[(size_t)g * 1024 + k]       = (_Float16)Wih1[(size_t)g * H_ + k];
        Wcat1[(size_t)g * 1024 + 512 + k] = (_Float16)Whh1[(size_t)g * H_ + k];
    }
}

// ---------------------------------------------------------------------------
// 16-block (one batch-group) barrier. Monotone counter, never reset.
// NO fences: data coherence is per-access (sc-flagged atomics); the
// preceding __syncthreads drains vmcnt so all sc-stores are acked at the
// coherence point before the arrive becomes visible.
__device__ __forceinline__ void group_barrier(int* c, int target) {
    __syncthreads();
    if (threadIdx.x == 0) {
        __hip_atomic_fetch_add(c, 1, __ATOMIC_RELAXED, __HIP_MEMORY_SCOPE_AGENT);
        while (__hip_atomic_load(c, __ATOMIC_RELAXED, __HIP_MEMORY_SCOPE_AGENT) < target)
            __builtin_amdgcn_s_sleep(1);
    }
    __syncthreads();
}

// ---------------------------------------------------------------------------
// Fused scan. Step u: L0 computes h0(u) (u<256), L1 computes h1(u-1) (u>=1).
// A-panel chunks (8 halfs each): x 0..15, h0 16..79, h1 80..143.
// L0 K-window: chunks 0..79 (20 ksteps, 5/wave; ksteps 0..3 = x part).
// L1 K-window: chunks 16..143 (32 ksteps, 8/wave; waves 0,1 = y0 part).
__global__ __launch_bounds__(256, 1) void gru_fused(
    const float* __restrict__ x,
    const _Float16* __restrict__ Wcat0, const _Float16* __restrict__ Wcat1,
    const float* __restrict__ bih0, const float* __restrict__ bhh0,
    const float* __restrict__ bih1, const float* __restrict__ bhh1,
    _Float16* __restrict__ h0ring,   // [2][B][H]
    _Float16* __restrict__ h1ring,   // [2][B][H]
    float* __restrict__ hT,          // [B][H] final layer-1 hidden (fp32)
    int* __restrict__ ctrbase) {
    __shared__ __attribute__((aligned(16))) _Float16 As[16 * 1152];
    __shared__ float ghp[4][16][100];
    __shared__ float anx[16][32];

    const int tid  = threadIdx.x;
    const int bg   = blockIdx.x & 15;
    const int cg   = blockIdx.x >> 4;
    const int wave = tid >> 6;
    const int lane = tid & 63;
    const int l15  = lane & 15;
    const int q    = lane >> 4;
    const int b0   = bg * 16;
    const int hc0  = cg * 32;
    int* myctr = (int*)((char*)ctrbase + bg * 128);

    // ---- W fragments in registers (B-operand: col n = l15, k = q*8+j) ----
    h8 wf0[5][6];
#pragma unroll
    for (int s = 0; s < 5; ++s) {
        const int kh = (wave * 5 + s) * 32 + q * 8;
#pragma unroll
        for (int nt = 0; nt < 6; ++nt) {
            const int grow = (nt >> 1) * H_ + hc0 + (nt & 1) * 16 + l15;
            wf0[s][nt] = *(const h8*)(Wcat0 + (size_t)grow * 640 + kh);
        }
    }
    h8 wf1[8][6];
#pragma unroll
    for (int s = 0; s < 8; ++s) {
        const int kh = (wave * 8 + s) * 32 + q * 8;
#pragma unroll
        for (int nt = 0; nt < 6; ++nt) {
            const int grow = (nt >> 1) * H_ + hc0 + (nt & 1) * 16 + l15;
            wf1[s][nt] = *(const h8*)(Wcat1 + (size_t)grow * 1024 + kh);
        }
    }
    // ---- per-thread epilogue biases (thread -> (row er, cols jj..jj+1)) ----
    float br0[2], bz0[2], bi0[2], bh0[2], br1[2], bz1[2], bi1[2], bh1[2];
    {
        const int jj = (tid & 15) * 2;
#pragma unroll
        for (int e = 0; e < 2; ++e) {
            const int col = hc0 + jj + e;
            br0[e] = bih0[col] + bhh0[col];
            bz0[e] = bih0[H_ + col] + bhh0[H_ + col];
            bi0[e] = bih0[2 * H_ + col];
            bh0[e] = bhh0[2 * H_ + col];
            br1[e] = bih1[col] + bhh1[col];
            bz1[e] = bih1[H_ + col] + bhh1[H_ + col];
            bi1[e] = bih1[2 * H_ + col];
            bh1[e] = bhh1[2 * H_ + col];
        }
    }

#pragma unroll 1
    for (int u = 0; u <= T_; ++u) {
        // ================= stage A-panel =================
        {
            const int r = tid >> 4, c16 = tid & 15;
            if (u < T_) {  // x_u -> chunks 0..15
                const float* xp = x + ((size_t)(b0 + r) * T_ + u) * D_ + c16 * 8;
                float4 v0 = *(const float4*)(xp);
                float4 v1 = *(const float4*)(xp + 4);
                h8 hx;
                hx[0] = (_Float16)v0.x; hx[1] = (_Float16)v0.y;
                hx[2] = (_Float16)v0.z; hx[3] = (_Float16)v0.w;
                hx[4] = (_Float16)v1.x; hx[5] = (_Float16)v1.y;
                hx[6] = (_Float16)v1.z; hx[7] = (_Float16)v1.w;
                *(h8*)&As[r * 1152 + swz(c16, r) * 8] = hx;
            }
            // h0(u-1) -> chunks 16..79   (parity (u-1)&1 == (u+1)&1)
            const _Float16* h0p = h0ring + (size_t)((u + 1) & 1) * (B_ * H_) + (size_t)(b0 + r) * H_;
#pragma unroll
            for (int i = 0; i < 4; ++i) {
                const int lc = c16 + i * 16;
                h8 hv = {};
                if (u > 0) hv = ld_h8_coh(h0p + lc * 8);
                *(h8*)&As[r * 1152 + swz(16 + lc, r) * 8] = hv;
            }
            // h1(u-2) -> chunks 80..143  (parity (u-2)&1 == u&1)
            const _Float16* h1p = h1ring + (size_t)(u & 1) * (B_ * H_) + (size_t)(b0 + r) * H_;
#pragma unroll
            for (int i = 0; i < 4; ++i) {
                const int lc = c16 + i * 16;
                h8 hv = {};
                if (u > 1) hv = ld_h8_coh(h1p + lc * 8);
                *(h8*)&As[r * 1152 + swz(80 + lc, r) * 8] = hv;
            }
        }
        __syncthreads();
        // ================= L0 MFMA =================
        if (u < T_) {
            f4 arz0 = {0,0,0,0}, arz1 = {0,0,0,0}, arz2 = {0,0,0,0}, arz3 = {0,0,0,0};
            f4 anx0 = {0,0,0,0}, anx1 = {0,0,0,0}, anh0 = {0,0,0,0}, anh1 = {0,0,0,0};
#pragma unroll
            for (int s = 0; s < 5; ++s) {
                const int kstep = wave * 5 + s;
                const int c = kstep * 4 + q;           // chunk 0..79
                h8 a = *(const h8*)&As[l15 * 1152 + swz(c, l15) * 8];
                arz0 = MFMA16(a, wf0[s][0], arz0);
                arz1 = MFMA16(a, wf0[s][1], arz1);
                arz2 = MFMA16(a, wf0[s][2], arz2);
                arz3 = MFMA16(a, wf0[s][3], arz3);
                if (kstep < 4) {                       // x part (wave 0 only)
                    anx0 = MFMA16(a, wf0[s][4], anx0);
                    anx1 = MFMA16(a, wf0[s][5], anx1);
                } else {                               // h part
                    anh0 = MFMA16(a, wf0[s][4], anh0);
                    anh1 = MFMA16(a, wf0[s][5], anh1);
                }
            }
#pragma unroll
            for (int i = 0; i < 4; ++i) {              // C/D: row=q*4+i, col=l15
                float* row = &ghp[wave][q * 4 + i][0];
                row[ 0 + l15] = arz0[i];
                row[16 + l15] = arz1[i];
                row[32 + l15] = arz2[i];
                row[48 + l15] = arz3[i];
                row[64 + l15] = anh0[i];
                row[80 + l15] = anh1[i];
            }
            if (wave == 0) {
#pragma unroll
                for (int i = 0; i < 4; ++i) {
                    anx[q * 4 + i][l15]      = anx0[i];
                    anx[q * 4 + i][16 + l15] = anx1[i];
                }
            }
        }
        __syncthreads();
        // ================= L0 epilogue: h0(u) =================
        if (u < T_) {
            const int er = tid >> 4;
            const int jj = (tid & 15) * 2;
            h2v out2;
#pragma unroll
            for (int e = 0; e < 2; ++e) {
                const int j = jj + e;
                float gr = 0.f, gz = 0.f, ghn = 0.f;
#pragma unroll
                for (int w = 0; w < 4; ++w) {
                    gr  += ghp[w][er][j];
                    gz  += ghp[w][er][32 + j];
                    ghn += ghp[w][er][64 + j];
                }
                const float gxn = anx[er][j];
                const float rr = sigmoid_f(gr + br0[e]);
                const float zz = sigmoid_f(gz + bz0[e]);
                const float nn = tanh_f(gxn + bi0[e] + rr * (ghn + bh0[e]));
                const int hcol = hc0 + j;
                const float hp = (float)As[er * 1152 + swz(16 + (hcol >> 3), er) * 8 + (hcol & 7)];
                out2[e] = (_Float16)((1.f - zz) * nn + zz * hp);
            }
            st_h2_coh(h0ring + (size_t)(u & 1) * (B_ * H_) + (size_t)(b0 + er) * H_ + hc0 + jj, out2);
        }
        __syncthreads();   // ghp reuse guard
        // ================= L1 MFMA =================
        if (u > 0) {
            f4 arz0 = {0,0,0,0}, arz1 = {0,0,0,0}, arz2 = {0,0,0,0}, arz3 = {0,0,0,0};
            f4 an0 = {0,0,0,0}, an1 = {0,0,0,0};   // nx for waves 0,1; nh for 2,3
#pragma unroll
            for (int s = 0; s < 8; ++s) {
                const int c = 16 + (wave * 8 + s) * 4 + q;   // chunk 16..143
                h8 a = *(const h8*)&As[l15 * 1152 + swz(c, l15) * 8];
                arz0 = MFMA16(a, wf1[s][0], arz0);
                arz1 = MFMA16(a, wf1[s][1], arz1);
                arz2 = MFMA16(a, wf1[s][2], arz2);
                arz3 = MFMA16(a, wf1[s][3], arz3);
                an0  = MFMA16(a, wf1[s][4], an0);
                an1  = MFMA16(a, wf1[s][5], an1);
            }
#pragma unroll
            for (int i = 0; i < 4; ++i) {
                float* row = &ghp[wave][q * 4 + i][0];
                row[ 0 + l15] = arz0[i];
                row[16 + l15] = arz1[i];
                row[32 + l15] = arz2[i];
                row[48 + l15] = arz3[i];
                row[64 + l15] = an0[i];
                row[80 + l15] = an1[i];
            }
        }
        __syncthreads();
        // ================= L1 epilogue: h1(u-1) =================
        if (u > 0) {
            const int er = tid >> 4;
            const int jj = (tid & 15) * 2;
            h2v out2;
            float hvf[2];
#pragma unroll
            for (int e = 0; e < 2; ++e) {
                const int j = jj + e;
                float gr = 0.f, gz = 0.f;
#pragma unroll
                for (int w = 0; w < 4; ++w) {
                    gr += ghp[w][er][j];
                    gz += ghp[w][er][32 + j];
                }
                const float gxn = ghp[0][er][64 + j] + ghp[1][er][64 + j];
                const float ghn = ghp[2][er][64 + j] + ghp[3][er][64 + j];
                const float rr = sigmoid_f(gr + br1[e]);
                const float zz = sigmoid_f(gz + bz1[e]);
                const float nn = tanh_f(gxn + bi1[e] + rr * (ghn + bh1[e]));
                const int hcol = hc0 + j;
                const float hp = (float)As[er * 1152 + swz(80 + (hcol >> 3), er) * 8 + (hcol & 7)];
                hvf[e] = (1.f - zz) * nn + zz * hp;
                out2[e] = (_Float16)hvf[e];
            }
            st_h2_coh(h1ring + (size_t)((u + 1) & 1) * (B_ * H_) + (size_t)(b0 + er) * H_ + hc0 + jj, out2);
            if (u == T_) {
                hT[(size_t)(b0 + er) * H_ + hc0 + jj]     = hvf[0];
                hT[(size_t)(b0 + er) * H_ + hc0 + jj + 1] = hvf[1];
            }
        }
        if (u < T_) group_barrier(myctr, 16 * (u + 1));
    }
}

// ---------------------------------------------------------------------------
__global__ __launch_bounds__(128) void head_kernel(
    const float* __restrict__ hT, const float* __restrict__ fc1_w,
    const float* __restrict__ fc1_b, const float* __restrict__ fc2_w,
    const float* __restrict__ fc2_b, float* __restrict__ out) {
    __shared__ float hs[512];
    __shared__ float a1[128];
    const int b = blockIdx.x, tid = threadIdx.x;
    for (int k = tid; k < H_; k += 128) {
        float v = hT[(size_t)b * H_ + k];
        hs[k] = v > 0.f ? v : 0.f;
    }
    __syncthreads();
    float acc = fc1_b[tid];
    const float* wr = fc1_w + (size_t)tid * H_;
    for (int k = 0; k < H_; k += 4) {
        float4 w = *(const float4*)(wr + k);
        acc += w.x * hs[k] + w.y * hs[k + 1] + w.z * hs[k + 2] + w.w * hs[k + 3];
    }
    a1[tid] = acc > 0.f ? acc : 0.f;
    __syncthreads();
    if (tid < 10) {
        float o = fc2_b[tid];
        const float* w2 = fc2_w + (size_t)tid * 128;
        for (int k = 0; k < 128; ++k) o += w2[k] * a1[k];
        out[(size_t)b * 10 + tid] = o;
    }
}

// ---------------------------------------------------------------------------
extern "C" void kernel_launch(void* const* d_in, const int* in_sizes, int n_in,
                              void* d_out, int out_size, void* d_ws, size_t ws_size,
                              hipStream_t stream) {
    const float* x    = (const float*)d_in[0];
    const float* Wih0 = (const float*)d_in[1];
    const float* Whh0 = (const float*)d_in[2];
    const float* bih0 = (const float*)d_in[3];
    const float* bhh0 = (const float*)d_in[4];
    const float* Wih1 = (const float*)d_in[5];
    const float* Whh1 = (const float*)d_in[6];
    const float* bih1 = (const float*)d_in[7];
    const float* bhh1 = (const float*)d_in[8];
    const float* fc1w = (const float*)d_in[9];
    const float* fc1b = (const float*)d_in[10];
    const float* fc2w = (const float*)d_in[11];
    const float* fc2b = (const float*)d_in[12];

    char* ws = (char*)d_ws;
    size_t off = 0;
    int* ctr = (int*)(ws + off); off += 16 * 128;              // 2 KB
    off = (off + 255) & ~(size_t)255;
    _Float16* Wcat0 = (_Float16*)(ws + off); off += (size_t)G3 * 640 * 2;   // 1.97 MB
    off = (off + 255) & ~(size_t)255;
    _Float16* Wcat1 = (_Float16*)(ws + off); off += (size_t)G3 * 1024 * 2;  // 3.15 MB
    off = (off + 255) & ~(size_t)255;
    _Float16* h0ring = (_Float16*)(ws + off); off += (size_t)2 * B_ * H_ * 2;  // 0.5 MB
    _Float16* h1ring = (_Float16*)(ws + off); off += (size_t)2 * B_ * H_ * 2;  // 0.5 MB
    float* hT = (float*)(ws + off); off += (size_t)B_ * H_ * 4;                // 0.5 MB
    // total ~6.7 MB

    hipMemsetAsync(ctr, 0, 16 * 128, stream);  // zero barrier counters

    hipLaunchKernelGGL(convert_weights, dim3(G3), dim3(256), 0, stream,
                       Wih0, Whh0, Wih1, Whh1, Wcat0, Wcat1);
    hipLaunchKernelGGL(gru_fused, dim3(256), dim3(256), 0, stream,
                       x, Wcat0, Wcat1, bih0, bhh0, bih1, bhh1,
                       h0ring, h1ring, hT, ctr);
    hipLaunchKernelGGL(head_kernel, dim3(B_), dim3(128), 0, stream,
                       hT, fc1w, fc1b, fc2w, fc2b, (float*)d_out);
}

// Round 4
// 1313.148 us; speedup vs baseline: 2.0680x; 1.2321x over previous
//
#include <hip/hip_runtime.h>
#include <hip/hip_fp16.h>

// GRU_23613730193671 on MI355X (gfx950) — round 4: coalesced coherent transport
// B=256 T=256 D=128 H=512; out = fc2(relu(fc1(relu(hT_layer1))))
//
// Round-3 result: PASS 1618 us (6.3 us/step), MfmaUtil 8.5%. Diagnosis: the
// h-ring exchange used per-lane ATOMIC loads/stores (4096x8B atomic-loads +
// 512x4B atomic-stores per block-step) which do NOT coalesce -> message-rate
// bound at the MALL; plus a serialized 16-way fetch_add barrier.
//
// Round-4 changes (transport only, same compute structure):
//  - h-ring loads: inline-asm global_load_dwordx4 sc0 sc1 (coherent at MALL,
//    wave-coalesced), batched 8/thread with one s_waitcnt vmcnt(0).
//  - h-ring stores: epilogues stage h into spare LDS (h0 -> consumed x-region,
//    h1 -> in place), then wave0 gathers and stores 64x16B sc0 sc1 per ring.
//  - barrier: per-(bg,cg) monotone flag store after vmcnt(0); wave0 polls all
//    16 group flags with ONE coalesced load + __all. No fetch_add, no fences.

#define B_  256
#define T_  256
#define D_  128
#define H_  512
#define G3  1536
#define BH  (B_ * H_)

typedef _Float16 h8  __attribute__((ext_vector_type(8)));
typedef _Float16 h2v __attribute__((ext_vector_type(2)));
typedef float    f4  __attribute__((ext_vector_type(4)));

#define MFMA16(a, b, c) __builtin_amdgcn_mfma_f32_16x16x32_f16((a), (b), (c), 0, 0, 0)

// rotate 16B chunks within aligned groups of 8 by row index -> breaks the
// power-of-2 row stride; 2 lanes/bank aliasing is free (m136).
__device__ __forceinline__ int swz(int c, int r) { return (c & ~7) | ((c + r) & 7); }

__device__ __forceinline__ float sigmoid_f(float v) { return 1.f / (1.f + __expf(-v)); }
__device__ __forceinline__ float tanh_f(float v) {
    float ex = __expf(2.f * v);
    return 1.f - 2.f / (ex + 1.f);
}

// ---- coherent (MALL) coalesced 16B loads, batched, single waitcnt ----
__device__ __forceinline__ void ld8_sc(
    const _Float16* p0, const _Float16* p1, const _Float16* p2, const _Float16* p3,
    const _Float16* p4, const _Float16* p5, const _Float16* p6, const _Float16* p7,
    h8& r0, h8& r1, h8& r2, h8& r3, h8& r4, h8& r5, h8& r6, h8& r7) {
    asm volatile(
        "global_load_dwordx4 %0, %8, off sc0 sc1\n\t"
        "global_load_dwordx4 %1, %9, off sc0 sc1\n\t"
        "global_load_dwordx4 %2, %10, off sc0 sc1\n\t"
        "global_load_dwordx4 %3, %11, off sc0 sc1\n\t"
        "global_load_dwordx4 %4, %12, off sc0 sc1\n\t"
        "global_load_dwordx4 %5, %13, off sc0 sc1\n\t"
        "global_load_dwordx4 %6, %14, off sc0 sc1\n\t"
        "global_load_dwordx4 %7, %15, off sc0 sc1\n\t"
        "s_waitcnt vmcnt(0)"
        : "=&v"(r0), "=&v"(r1), "=&v"(r2), "=&v"(r3),
          "=&v"(r4), "=&v"(r5), "=&v"(r6), "=&v"(r7)
        : "v"(p0), "v"(p1), "v"(p2), "v"(p3),
          "v"(p4), "v"(p5), "v"(p6), "v"(p7)
        : "memory");
}
__device__ __forceinline__ void ld4_sc(
    const _Float16* p0, const _Float16* p1, const _Float16* p2, const _Float16* p3,
    h8& r0, h8& r1, h8& r2, h8& r3) {
    asm volatile(
        "global_load_dwordx4 %0, %4, off sc0 sc1\n\t"
        "global_load_dwordx4 %1, %5, off sc0 sc1\n\t"
        "global_load_dwordx4 %2, %6, off sc0 sc1\n\t"
        "global_load_dwordx4 %3, %7, off sc0 sc1\n\t"
        "s_waitcnt vmcnt(0)"
        : "=&v"(r0), "=&v"(r1), "=&v"(r2), "=&v"(r3)
        : "v"(p0), "v"(p1), "v"(p2), "v"(p3)
        : "memory");
}
// coherent 16B store (fire-and-forget; drained by vmcnt before flag)
__device__ __forceinline__ void st16_sc(_Float16* p, h8 v) {
    asm volatile("global_store_dwordx4 %0, %1, off sc0 sc1" :: "v"(p), "v"(v) : "memory");
}

// ---------------------------------------------------------------------------
__global__ void convert_weights(const float* __restrict__ Wih0,
                                const float* __restrict__ Whh0,
                                const float* __restrict__ Wih1,
                                const float* __restrict__ Whh1,
                                _Float16* __restrict__ Wcat0,
                                _Float16* __restrict__ Wcat1) {
    int g = blockIdx.x;  // 0..1535 (gate-row)
    for (int k = threadIdx.x; k < D_; k += blockDim.x)
        Wcat0[(size_t)g * 640 + k] = (_Float16)Wih0[(size_t)g * D_ + k];
    for (int k = threadIdx.x; k < H_; k += blockDim.x) {
        Wcat0[(size_t)g * 640 + 128 + k]  = (_Float16)Whh0[(size_t)g * H_ + k];
        Wcat1[(size_t)g * 1024 + k]       = (_Float16)Wih1[(size_t)g * H_ + k];
        Wcat1[(size_t)g * 1024 + 512 + k] = (_Float16)Whh1[(size_t)g * H_ + k];
    }
}

// ---------------------------------------------------------------------------
// Fused scan. Step u: L0 computes h0(u) (u<256), L1 computes h1(u-1) (u>=1).
// A-panel chunks (8 halfs each): x 0..15, h0 16..79, h1 80..143.
// L0 K-window: chunks 0..79 (20 ksteps, 5/wave; ksteps 0..3 = x part).
// L1 K-window: chunks 16..143 (32 ksteps, 8/wave; waves 0,1 = y0 part).
__global__ __launch_bounds__(256, 1) void gru_fused(
    const float* __restrict__ x,
    const _Float16* __restrict__ Wcat0, const _Float16* __restrict__ Wcat1,
    const float* __restrict__ bih0, const float* __restrict__ bhh0,
    const float* __restrict__ bih1, const float* __restrict__ bhh1,
    _Float16* __restrict__ h0ring,   // [2][B][H]
    _Float16* __restrict__ h1ring,   // [2][B][H]
    float* __restrict__ hT,          // [B][H] final layer-1 hidden (fp32)
    int* __restrict__ flagbase) {    // [16 bg][16 cg] monotone step flags
    __shared__ __attribute__((aligned(16))) _Float16 As[16 * 1152];
    __shared__ float ghp[4][16][100];
    __shared__ float anx[16][32];

    const int tid  = threadIdx.x;
    const int bg   = blockIdx.x & 15;
    const int cg   = blockIdx.x >> 4;
    const int wave = tid >> 6;
    const int lane = tid & 63;
    const int l15  = lane & 15;
    const int q    = lane >> 4;
    const int b0   = bg * 16;
    const int hc0  = cg * 32;
    int* flags = flagbase + bg * 16;

    // ---- W fragments in registers (B-operand: col n = l15, k = q*8+j) ----
    h8 wf0[5][6];
#pragma unroll
    for (int s = 0; s < 5; ++s) {
        const int kh = (wave * 5 + s) * 32 + q * 8;
#pragma unroll
        for (int nt = 0; nt < 6; ++nt) {
            const int grow = (nt >> 1) * H_ + hc0 + (nt & 1) * 16 + l15;
            wf0[s][nt] = *(const h8*)(Wcat0 + (size_t)grow * 640 + kh);
        }
    }
    h8 wf1[8][6];
#pragma unroll
    for (int s = 0; s < 8; ++s) {
        const int kh = (wave * 8 + s) * 32 + q * 8;
#pragma unroll
        for (int nt = 0; nt < 6; ++nt) {
            const int grow = (nt >> 1) * H_ + hc0 + (nt & 1) * 16 + l15;
            wf1[s][nt] = *(const h8*)(Wcat1 + (size_t)grow * 1024 + kh);
        }
    }
    // ---- per-thread epilogue biases (thread -> (row er, cols jj..jj+1)) ----
    float br0[2], bz0[2], bi0[2], bh0[2], br1[2], bz1[2], bi1[2], bh1[2];
    {
        const int jj = (tid & 15) * 2;
#pragma unroll
        for (int e = 0; e < 2; ++e) {
            const int col = hc0 + jj + e;
            br0[e] = bih0[col] + bhh0[col];
            bz0[e] = bih0[H_ + col] + bhh0[H_ + col];
            bi0[e] = bih0[2 * H_ + col];
            bh0[e] = bhh0[2 * H_ + col];
            br1[e] = bih1[col] + bhh1[col];
            bz1[e] = bih1[H_ + col] + bhh1[H_ + col];
            bi1[e] = bih1[2 * H_ + col];
            bh1[e] = bhh1[2 * H_ + col];
        }
    }

#pragma unroll 1
    for (int u = 0; u <= T_; ++u) {
        // ================= stage A-panel =================
        {
            const int r = tid >> 4, c16 = tid & 15;
            if (u < T_) {  // x_u -> chunks 0..15 (ordinary cached loads)
                const float* xp = x + ((size_t)(b0 + r) * T_ + u) * D_ + c16 * 8;
                float4 v0 = *(const float4*)(xp);
                float4 v1 = *(const float4*)(xp + 4);
                h8 hx;
                hx[0] = (_Float16)v0.x; hx[1] = (_Float16)v0.y;
                hx[2] = (_Float16)v0.z; hx[3] = (_Float16)v0.w;
                hx[4] = (_Float16)v1.x; hx[5] = (_Float16)v1.y;
                hx[6] = (_Float16)v1.z; hx[7] = (_Float16)v1.w;
                *(h8*)&As[r * 1152 + swz(c16, r) * 8] = hx;
            }
            // h0(u-1) parity (u+1)&1 -> chunks 16..79 ; h1(u-2) parity u&1 -> 80..143
            const _Float16* h0p = h0ring + (size_t)((u + 1) & 1) * BH + (size_t)(b0 + r) * H_;
            const _Float16* h1p = h1ring + (size_t)(u & 1) * BH + (size_t)(b0 + r) * H_;
            h8 a0 = {}, a1 = {}, a2 = {}, a3 = {}, c0 = {}, c1 = {}, c2 = {}, c3 = {};
            if (u > 1) {
                ld8_sc(h0p + c16 * 8, h0p + (c16 + 16) * 8, h0p + (c16 + 32) * 8, h0p + (c16 + 48) * 8,
                       h1p + c16 * 8, h1p + (c16 + 16) * 8, h1p + (c16 + 32) * 8, h1p + (c16 + 48) * 8,
                       a0, a1, a2, a3, c0, c1, c2, c3);
            } else if (u == 1) {
                ld4_sc(h0p + c16 * 8, h0p + (c16 + 16) * 8, h0p + (c16 + 32) * 8, h0p + (c16 + 48) * 8,
                       a0, a1, a2, a3);
            }
            *(h8*)&As[r * 1152 + swz(16 + c16,      r) * 8] = a0;
            *(h8*)&As[r * 1152 + swz(16 + c16 + 16, r) * 8] = a1;
            *(h8*)&As[r * 1152 + swz(16 + c16 + 32, r) * 8] = a2;
            *(h8*)&As[r * 1152 + swz(16 + c16 + 48, r) * 8] = a3;
            *(h8*)&As[r * 1152 + swz(80 + c16,      r) * 8] = c0;
            *(h8*)&As[r * 1152 + swz(80 + c16 + 16, r) * 8] = c1;
            *(h8*)&As[r * 1152 + swz(80 + c16 + 32, r) * 8] = c2;
            *(h8*)&As[r * 1152 + swz(80 + c16 + 48, r) * 8] = c3;
        }
        __syncthreads();
        // ================= L0 MFMA =================
        if (u < T_) {
            f4 arz0 = {0,0,0,0}, arz1 = {0,0,0,0}, arz2 = {0,0,0,0}, arz3 = {0,0,0,0};
            f4 anx0 = {0,0,0,0}, anx1 = {0,0,0,0}, anh0 = {0,0,0,0}, anh1 = {0,0,0,0};
#pragma unroll
            for (int s = 0; s < 5; ++s) {
                const int kstep = wave * 5 + s;
                const int c = kstep * 4 + q;           // chunk 0..79
                h8 a = *(const h8*)&As[l15 * 1152 + swz(c, l15) * 8];
                arz0 = MFMA16(a, wf0[s][0], arz0);
                arz1 = MFMA16(a, wf0[s][1], arz1);
                arz2 = MFMA16(a, wf0[s][2], arz2);
                arz3 = MFMA16(a, wf0[s][3], arz3);
                if (kstep < 4) {                       // x part (wave 0 only)
                    anx0 = MFMA16(a, wf0[s][4], anx0);
                    anx1 = MFMA16(a, wf0[s][5], anx1);
                } else {                               // h part
                    anh0 = MFMA16(a, wf0[s][4], anh0);
                    anh1 = MFMA16(a, wf0[s][5], anh1);
                }
            }
#pragma unroll
            for (int i = 0; i < 4; ++i) {              // C/D: row=q*4+i, col=l15
                float* row = &ghp[wave][q * 4 + i][0];
                row[ 0 + l15] = arz0[i];
                row[16 + l15] = arz1[i];
                row[32 + l15] = arz2[i];
                row[48 + l15] = arz3[i];
                row[64 + l15] = anh0[i];
                row[80 + l15] = anh1[i];
            }
            if (wave == 0) {
#pragma unroll
                for (int i = 0; i < 4; ++i) {
                    anx[q * 4 + i][l15]      = anx0[i];
                    anx[q * 4 + i][16 + l15] = anx1[i];
                }
            }
        }
        __syncthreads();
        // ================= L0 epilogue: h0(u) -> LDS x-region =================
        if (u < T_) {
            const int er = tid >> 4;
            const int jj = (tid & 15) * 2;
            h2v out2;
#pragma unroll
            for (int e = 0; e < 2; ++e) {
                const int j = jj + e;
                float gr = 0.f, gz = 0.f, ghn = 0.f;
#pragma unroll
                for (int w = 0; w < 4; ++w) {
                    gr  += ghp[w][er][j];
                    gz  += ghp[w][er][32 + j];
                    ghn += ghp[w][er][64 + j];
                }
                const float gxn = anx[er][j];
                const float rr = sigmoid_f(gr + br0[e]);
                const float zz = sigmoid_f(gz + bz0[e]);
                const float nn = tanh_f(gxn + bi0[e] + rr * (ghn + bh0[e]));
                const int hcol = hc0 + j;
                const float hp = (float)As[er * 1152 + swz(16 + (hcol >> 3), er) * 8 + (hcol & 7)];
                out2[e] = (_Float16)((1.f - zz) * nn + zz * hp);
            }
            // stage into consumed x-region (chunks 0..7 after swz), local cols
            *(h2v*)&As[er * 1152 + swz(jj >> 3, er) * 8 + (jj & 7)] = out2;
        }
        __syncthreads();   // ghp reuse guard + h0 stage visible
        // ================= L1 MFMA (+ wave0: coalesced h0 ring store) ========
        if (wave == 0 && u < T_) {
            const int row = lane >> 2, ch = lane & 3;
            h8 v = *(const h8*)&As[row * 1152 + swz(ch, row) * 8];
            st16_sc(h0ring + (size_t)(u & 1) * BH + (size_t)(b0 + row) * H_ + hc0 + ch * 8, v);
        }
        if (u > 0) {
            f4 arz0 = {0,0,0,0}, arz1 = {0,0,0,0}, arz2 = {0,0,0,0}, arz3 = {0,0,0,0};
            f4 an0 = {0,0,0,0}, an1 = {0,0,0,0};   // nx for waves 0,1; nh for 2,3
#pragma unroll
            for (int s = 0; s < 8; ++s) {
                const int c = 16 + (wave * 8 + s) * 4 + q;   // chunk 16..143
                h8 a = *(const h8*)&As[l15 * 1152 + swz(c, l15) * 8];
                arz0 = MFMA16(a, wf1[s][0], arz0);
                arz1 = MFMA16(a, wf1[s][1], arz1);
                arz2 = MFMA16(a, wf1[s][2], arz2);
                arz3 = MFMA16(a, wf1[s][3], arz3);
                an0  = MFMA16(a, wf1[s][4], an0);
                an1  = MFMA16(a, wf1[s][5], an1);
            }
#pragma unroll
            for (int i = 0; i < 4; ++i) {
                float* row = &ghp[wave][q * 4 + i][0];
                row[ 0 + l15] = arz0[i];
                row[16 + l15] = arz1[i];
                row[32 + l15] = arz2[i];
                row[48 + l15] = arz3[i];
                row[64 + l15] = an0[i];
                row[80 + l15] = an1[i];
            }
        }
        __syncthreads();
        // ================= L1 epilogue: h1(u-1) -> in-place LDS ==============
        if (u > 0) {
            const int er = tid >> 4;
            const int jj = (tid & 15) * 2;
            h2v out2;
            float hvf[2];
#pragma unroll
            for (int e = 0; e < 2; ++e) {
                const int j = jj + e;
                float gr = 0.f, gz = 0.f;
#pragma unroll
                for (int w = 0; w < 4; ++w) {
                    gr += ghp[w][er][j];
                    gz += ghp[w][er][32 + j];
                }
                const float gxn = ghp[0][er][64 + j] + ghp[1][er][64 + j];
                const float ghn = ghp[2][er][64 + j] + ghp[3][er][64 + j];
                const float rr = sigmoid_f(gr + br1[e]);
                const float zz = sigmoid_f(gz + bz1[e]);
                const float nn = tanh_f(gxn + bi1[e] + rr * (ghn + bh1[e]));
                const int hcol = hc0 + j;
                const float hp = (float)As[er * 1152 + swz(80 + (hcol >> 3), er) * 8 + (hcol & 7)];
                hvf[e] = (1.f - zz) * nn + zz * hp;
                out2[e] = (_Float16)hvf[e];
            }
            // overwrite the exact element pair this thread just read (1:1 map)
            const int hcol0 = hc0 + jj;
            *(h2v*)&As[er * 1152 + swz(80 + (hcol0 >> 3), er) * 8 + (hcol0 & 7)] = out2;
            if (u == T_) {
                hT[(size_t)(b0 + er) * H_ + hc0 + jj]     = hvf[0];
                hT[(size_t)(b0 + er) * H_ + hc0 + jj + 1] = hvf[1];
            }
        }
        // ================= publish + flag + poll =================
        if (u < T_) {
            __syncthreads();   // h1 stage visible to wave0
            if (wave == 0) {
                if (u > 0) {   // coalesced h1 ring store (parity (u+1)&1)
                    const int row = lane >> 2, ch = lane & 3;
                    const int gch = 80 + (hc0 >> 3) + ch;
                    h8 v = *(const h8*)&As[row * 1152 + swz(gch, row) * 8];
                    st16_sc(h1ring + (size_t)((u + 1) & 1) * BH + (size_t)(b0 + row) * H_ + hc0 + ch * 8, v);
                }
                asm volatile("s_waitcnt vmcnt(0)" ::: "memory");   // all sc-stores acked
                if (lane == 0)
                    __hip_atomic_store(flags + cg, u + 1, __ATOMIC_RELAXED, __HIP_MEMORY_SCOPE_AGENT);
                int ok;
                do {
                    __builtin_amdgcn_s_sleep(1);
                    int f = 0x7fffffff;
                    if (lane < 16)
                        f = __hip_atomic_load(flags + lane, __ATOMIC_RELAXED, __HIP_MEMORY_SCOPE_AGENT);
                    ok = __all(f >= u + 1);
                } while (!ok);
            }
            __syncthreads();
        }
    }
}

// ---------------------------------------------------------------------------
__global__ __launch_bounds__(128) void head_kernel(
    const float* __restrict__ hT, const float* __restrict__ fc1_w,
    const float* __restrict__ fc1_b, const float* __restrict__ fc2_w,
    const float* __restrict__ fc2_b, float* __restrict__ out) {
    __shared__ float hs[512];
    __shared__ float a1[128];
    const int b = blockIdx.x, tid = threadIdx.x;
    for (int k = tid; k < H_; k += 128) {
        float v = hT[(size_t)b * H_ + k];
        hs[k] = v > 0.f ? v : 0.f;
    }
    __syncthreads();
    float acc = fc1_b[tid];
    const float* wr = fc1_w + (size_t)tid * H_;
    for (int k = 0; k < H_; k += 4) {
        float4 w = *(const float4*)(wr + k);
        acc += w.x * hs[k] + w.y * hs[k + 1] + w.z * hs[k + 2] + w.w * hs[k + 3];
    }
    a1[tid] = acc > 0.f ? acc : 0.f;
    __syncthreads();
    if (tid < 10) {
        float o = fc2_b[tid];
        const float* w2 = fc2_w + (size_t)tid * 128;
        for (int k = 0; k < 128; ++k) o += w2[k] * a1[k];
        out[(size_t)b * 10 + tid] = o;
    }
}

// ---------------------------------------------------------------------------
extern "C" void kernel_launch(void* const* d_in, const int* in_sizes, int n_in,
                              void* d_out, int out_size, void* d_ws, size_t ws_size,
                              hipStream_t stream) {
    const float* x    = (const float*)d_in[0];
    const float* Wih0 = (const float*)d_in[1];
    const float* Whh0 = (const float*)d_in[2];
    const float* bih0 = (const float*)d_in[3];
    const float* bhh0 = (const float*)d_in[4];
    const float* Wih1 = (const float*)d_in[5];
    const float* Whh1 = (const float*)d_in[6];
    const float* bih1 = (const float*)d_in[7];
    const float* bhh1 = (const float*)d_in[8];
    const float* fc1w = (const float*)d_in[9];
    const float* fc1b = (const float*)d_in[10];
    const float* fc2w = (const float*)d_in[11];
    const float* fc2b = (const float*)d_in[12];

    char* ws = (char*)d_ws;
    size_t off = 0;
    int* flags = (int*)(ws + off); off += 16 * 16 * 4;         // 1 KB
    off = (off + 255) & ~(size_t)255;
    _Float16* Wcat0 = (_Float16*)(ws + off); off += (size_t)G3 * 640 * 2;   // 1.97 MB
    off = (off + 255) & ~(size_t)255;
    _Float16* Wcat1 = (_Float16*)(ws + off); off += (size_t)G3 * 1024 * 2;  // 3.15 MB
    off = (off + 255) & ~(size_t)255;
    _Float16* h0ring = (_Float16*)(ws + off); off += (size_t)2 * BH * 2;    // 0.5 MB
    _Float16* h1ring = (_Float16*)(ws + off); off += (size_t)2 * BH * 2;    // 0.5 MB
    float* hT = (float*)(ws + off); off += (size_t)BH * 4;                  // 0.5 MB
    // total ~6.7 MB

    hipMemsetAsync(flags, 0, 16 * 16 * 4, stream);  // zero step flags

    hipLaunchKernelGGL(convert_weights, dim3(G3), dim3(256), 0, stream,
                       Wih0, Whh0, Wih1, Whh1, Wcat0, Wcat1);
    hipLaunchKernelGGL(gru_fused, dim3(256), dim3(256), 0, stream,
                       x, Wcat0, Wcat1, bih0, bhh0, bih1, bhh1,
                       h0ring, h1ring, hT, flags);
    hipLaunchKernelGGL(head_kernel, dim3(B_), dim3(128), 0, stream,
                       hT, fc1w, fc1b, fc2w, fc2b, (float*)d_out);
}